// Round 1
// baseline (2805.129 us; speedup 1.0000x reference)
//
#include <hip/hip_runtime.h>
#include <hip/hip_bf16.h>
#include <cmath>
#include <cstdint>

#define B_ 4
#define N_ 2048
#define M_ 512
#define H_ 12
#define D_ 64
#define DIM_ 768
#define QKV_ 2304
#define SCALE_ 0.125f
#define NEG_ -1e9f
#define TEMP_ 24.0f

// ---------------------------------------------------------------------------
// QKV GEMM: A [totalRows, 768] @ W_qkv [768, 2304], scatter epilogue into
// q/k/v laid out [B, H, rowsPerB, 64].
// BM=BN=64, BK=16, 256 threads, 4x4 micro-tile.
// ---------------------------------------------------------------------------
__global__ __launch_bounds__(256) void qkv_gemm(
    const float* __restrict__ A, const float* __restrict__ W,
    int rowsPerB, int totalRows,
    float* __restrict__ q, float* __restrict__ k, float* __restrict__ v) {
  __shared__ float As[16][72];  // [kk][m], row stride 72 floats = 288B (16B mult)
  __shared__ float Bs[16][64];  // [kk][n]
  const int r0 = blockIdx.y * 64;
  const int c0 = blockIdx.x * 64;
  const int tid = threadIdx.x;
  const int tx = tid & 15, ty = tid >> 4;
  float acc[4][4] = {};
  for (int k0 = 0; k0 < DIM_; k0 += 16) {
    {
      int e = tid * 4;
      int row = e >> 4;       // 0..63
      int kk = e & 15;        // 0,4,8,12
      float4 av = make_float4(0.f, 0.f, 0.f, 0.f);
      int gr = r0 + row;
      if (gr < totalRows) av = *(const float4*)(A + (size_t)gr * DIM_ + k0 + kk);
      As[kk + 0][row] = av.x; As[kk + 1][row] = av.y;
      As[kk + 2][row] = av.z; As[kk + 3][row] = av.w;
      int kk2 = e >> 6;       // 0..15
      int cc = e & 63;
      *(float4*)(&Bs[kk2][cc]) =
          *(const float4*)(W + (size_t)(k0 + kk2) * QKV_ + c0 + cc);
    }
    __syncthreads();
#pragma unroll
    for (int kk = 0; kk < 16; kk++) {
      float4 a4 = *(const float4*)(&As[kk][ty * 4]);
      float4 b4 = *(const float4*)(&Bs[kk][tx * 4]);
      float a[4] = {a4.x, a4.y, a4.z, a4.w};
      float b[4] = {b4.x, b4.y, b4.z, b4.w};
#pragma unroll
      for (int i = 0; i < 4; i++)
#pragma unroll
        for (int j = 0; j < 4; j++) acc[i][j] += a[i] * b[j];
    }
    __syncthreads();
  }
  // scatter: column c -> (which, h, d); block spans exactly one (which, h)
  const int c_base = c0 + tx * 4;
  const int which = c_base / DIM_;
  const int rem = c_base - which * DIM_;
  const int h = rem >> 6;
  const int d0 = rem & 63;
  float* dst = which == 0 ? q : (which == 1 ? k : v);
#pragma unroll
  for (int i = 0; i < 4; i++) {
    int gr = r0 + ty * 4 + i;
    if (gr >= totalRows) break;
    int b = gr / rowsPerB;
    int n = gr - b * rowsPerB;
    size_t base = (((size_t)b * H_ + h) * rowsPerB + n) * D_ + d0;
    float4 r = {acc[i][0], acc[i][1], acc[i][2], acc[i][3]};
    *(float4*)(dst + base) = r;
  }
}

// ---------------------------------------------------------------------------
// Output projection GEMM: A [totalRows, 768] @ W_out [768,768] + bias.
// ---------------------------------------------------------------------------
__global__ __launch_bounds__(256) void proj_gemm(
    const float* __restrict__ A, const float* __restrict__ W,
    const float* __restrict__ bias, float* __restrict__ C, int totalRows) {
  __shared__ float As[16][72];
  __shared__ float Bs[16][64];
  const int r0 = blockIdx.y * 64;
  const int c0 = blockIdx.x * 64;
  const int tid = threadIdx.x;
  const int tx = tid & 15, ty = tid >> 4;
  float acc[4][4] = {};
  for (int k0 = 0; k0 < DIM_; k0 += 16) {
    {
      int e = tid * 4;
      int row = e >> 4;
      int kk = e & 15;
      float4 av = make_float4(0.f, 0.f, 0.f, 0.f);
      int gr = r0 + row;
      if (gr < totalRows) av = *(const float4*)(A + (size_t)gr * DIM_ + k0 + kk);
      As[kk + 0][row] = av.x; As[kk + 1][row] = av.y;
      As[kk + 2][row] = av.z; As[kk + 3][row] = av.w;
      int kk2 = e >> 6;
      int cc = e & 63;
      *(float4*)(&Bs[kk2][cc]) =
          *(const float4*)(W + (size_t)(k0 + kk2) * DIM_ + c0 + cc);
    }
    __syncthreads();
#pragma unroll
    for (int kk = 0; kk < 16; kk++) {
      float4 a4 = *(const float4*)(&As[kk][ty * 4]);
      float4 b4 = *(const float4*)(&Bs[kk][tx * 4]);
      float a[4] = {a4.x, a4.y, a4.z, a4.w};
      float b[4] = {b4.x, b4.y, b4.z, b4.w};
#pragma unroll
      for (int i = 0; i < 4; i++)
#pragma unroll
        for (int j = 0; j < 4; j++) acc[i][j] += a[i] * b[j];
    }
    __syncthreads();
  }
  const int cb = c0 + tx * 4;
  float4 bv = *(const float4*)(bias + cb);
#pragma unroll
  for (int i = 0; i < 4; i++) {
    int gr = r0 + ty * 4 + i;
    if (gr >= totalRows) break;
    float4 r = {acc[i][0] + bv.x, acc[i][1] + bv.y,
                acc[i][2] + bv.z, acc[i][3] + bv.w};
    *(float4*)(C + (size_t)gr * DIM_ + cb) = r;
  }
}

// ---------------------------------------------------------------------------
// Branch 1: per (b, h, 16-row n-tile):
//   dots = t_q . k_k^T * SCALE, masked; two softmaxes over M=512;
//   writes attn_hot (transposed, *krd) to out3; attn (*krd) @ k_v -> att_m.
// ---------------------------------------------------------------------------
__global__ __launch_bounds__(256) void branch1(
    const float* __restrict__ tq, const float* __restrict__ kkp,
    const float* __restrict__ kvp, const float* __restrict__ krd,
    const int* __restrict__ mask, float* __restrict__ out3,
    float* __restrict__ attm) {
  const int b = blockIdx.z, h = blockIdx.y, n0 = blockIdx.x * 16;
  __shared__ float qs[16][65];
  __shared__ float ks[64][65];
  __shared__ float sc[16][513];
  __shared__ float rowM[16], rowS1[16], rowS2[16];
  const size_t bh = (size_t)b * H_ + h;
  const float* tq0 = tq + (bh * N_ + n0) * D_;
  const float* kk0 = kkp + bh * M_ * D_;
  const float* kv0 = kvp + bh * M_ * D_;
  const float* krd0 = krd + bh * M_ * N_;          // [m][n]
  const int* mask0 = mask + (bh * N_ + n0) * M_;   // [n][m]
  const int tid = threadIdx.x;

  for (int e = tid; e < 16 * 64; e += 256) qs[e >> 6][e & 63] = tq0[e];

  // phase 1: dots (16 x 512), 2x2 micro-tile over 64-wide k_k chunks
  const int i0 = (tid & 7) * 2, jj0 = (tid >> 3) * 2;
  for (int j0 = 0; j0 < M_; j0 += 64) {
    __syncthreads();
    for (int e = tid; e < 64 * 64; e += 256)
      ks[e >> 6][e & 63] = kk0[(size_t)j0 * D_ + e];
    __syncthreads();
    float a00 = 0, a01 = 0, a10 = 0, a11 = 0;
#pragma unroll
    for (int kk = 0; kk < 64; kk++) {
      float q0v = qs[i0][kk], q1v = qs[i0 + 1][kk];
      float k0v = ks[jj0][kk], k1v = ks[jj0 + 1][kk];
      a00 += q0v * k0v; a01 += q0v * k1v;
      a10 += q1v * k0v; a11 += q1v * k1v;
    }
    sc[i0][j0 + jj0] = a00; sc[i0][j0 + jj0 + 1] = a01;
    sc[i0 + 1][j0 + jj0] = a10; sc[i0 + 1][j0 + jj0 + 1] = a11;
  }
  __syncthreads();
  // phase 2: mask + scale (coalesced mask read)
  for (int e = tid; e < 16 * 512; e += 256) {
    int i = e >> 9, j = e & 511;
    float d = sc[i][j] * SCALE_;
    if (mask0[(size_t)i * M_ + j]) d = NEG_;
    sc[i][j] = d;
  }
  __syncthreads();
  // phase 3: per-row max and both softmax denominators
  {
    int i = tid >> 4, jl = tid & 15;
    float mx = -INFINITY;
    for (int j = jl; j < 512; j += 16) mx = fmaxf(mx, sc[i][j]);
#pragma unroll
    for (int o = 8; o >= 1; o >>= 1) mx = fmaxf(mx, __shfl_xor(mx, o, 16));
    float s1 = 0, s2 = 0;
    for (int j = jl; j < 512; j += 16) {
      float d = sc[i][j] - mx;
      s1 += expf(d * TEMP_);
      s2 += expf(d);
    }
#pragma unroll
    for (int o = 8; o >= 1; o >>= 1) {
      s1 += __shfl_xor(s1, o, 16);
      s2 += __shfl_xor(s2, o, 16);
    }
    if (jl == 0) { rowM[i] = mx; rowS1[i] = 1.f / s1; rowS2[i] = 1.f / s2; }
  }
  __syncthreads();
  // phase 4: write attn_hot (out3, [m][n] order, coalesced in n),
  //          overwrite sc with p2 = softmax(dots)*krd
  for (int e = tid; e < 16 * 512; e += 256) {
    int i = e & 15, j = e >> 4;
    float d = sc[i][j];
    float mx = rowM[i];
    float kr = krd0[(size_t)j * N_ + n0 + i];
    float p1 = expf((d - mx) * TEMP_) * rowS1[i] * kr;
    out3[(bh * M_ + j) * N_ + n0 + i] = p1;
    sc[i][j] = expf(d - mx) * rowS2[i] * kr;
  }
  __syncthreads();
  // phase 5: o = p2 @ k_v  (16 x 64), 2dd x 2i micro-tile
  const int dd2 = (tid & 31) * 2, g = tid >> 5;
  float o00 = 0, o01 = 0, o10 = 0, o11 = 0;
  for (int j0 = 0; j0 < M_; j0 += 64) {
    __syncthreads();
    for (int e = tid; e < 64 * 64; e += 256)
      ks[e >> 6][e & 63] = kv0[(size_t)j0 * D_ + e];
    __syncthreads();
#pragma unroll
    for (int j = 0; j < 64; j++) {
      float pa = sc[g][j0 + j], pb = sc[g + 8][j0 + j];
      float v0 = ks[j][dd2], v1 = ks[j][dd2 + 1];
      o00 += pa * v0; o01 += pa * v1;
      o10 += pb * v0; o11 += pb * v1;
    }
  }
  size_t ab = ((size_t)b * N_ + n0) * DIM_ + (size_t)h * D_;
  attm[ab + (size_t)g * DIM_ + dd2] = o00;
  attm[ab + (size_t)g * DIM_ + dd2 + 1] = o01;
  attm[ab + (size_t)(g + 8) * DIM_ + dd2] = o10;
  attm[ab + (size_t)(g + 8) * DIM_ + dd2 + 1] = o11;
}

// ---------------------------------------------------------------------------
// Branch 2: flash-style over N=2048. k_attn = softmax_n(k_q.t_k^T, mask^T)*krd,
// out = k_attn @ t_v. krd folded into numerator only.
// ---------------------------------------------------------------------------
__global__ __launch_bounds__(256) void branch2(
    const float* __restrict__ kq, const float* __restrict__ tk,
    const float* __restrict__ tv, const float* __restrict__ krd,
    const int* __restrict__ mask, float* __restrict__ km) {
  const int b = blockIdx.z, h = blockIdx.y, m0 = blockIdx.x * 16;
  __shared__ float qs[16][65];
  __shared__ float ts[64][65];
  __shared__ float vs[64][65];
  __shared__ float sp[16][65];
  __shared__ unsigned char msk[64][16];
  __shared__ float rowM[16], rowL[16], alpha_s[16];
  const size_t bh = (size_t)b * H_ + h;
  const float* kq0 = kq + (bh * M_ + m0) * D_;
  const float* tk0 = tk + bh * N_ * D_;
  const float* tv0 = tv + bh * N_ * D_;
  const float* krd0 = krd + (bh * M_ + m0) * N_;  // [m][n]
  const int* mask0 = mask + bh * N_ * M_;         // [n][m]
  const int tid = threadIdx.x;
  for (int e = tid; e < 16 * 64; e += 256) qs[e >> 6][e & 63] = kq0[e];
  if (tid < 16) { rowM[tid] = -INFINITY; rowL[tid] = 0.f; }
  float o00 = 0, o01 = 0, o10 = 0, o11 = 0;
  const int dd2 = (tid & 31) * 2, g = tid >> 5;
  const int i0 = (tid & 7) * 2, jj0 = (tid >> 3) * 2;
  for (int j0 = 0; j0 < N_; j0 += 64) {
    __syncthreads();
    for (int e = tid; e < 64 * 64; e += 256) {
      ts[e >> 6][e & 63] = tk0[(size_t)j0 * D_ + e];
      vs[e >> 6][e & 63] = tv0[(size_t)j0 * D_ + e];
    }
    for (int e = tid; e < 64 * 16; e += 256) {
      int n = e >> 4, m = e & 15;
      msk[n][m] = (unsigned char)(mask0[(size_t)(j0 + n) * M_ + m0 + m] != 0);
    }
    __syncthreads();
    // s tile (16 m-rows x 64 n-cols), 2x2 micro
    float a00 = 0, a01 = 0, a10 = 0, a11 = 0;
#pragma unroll
    for (int kk = 0; kk < 64; kk++) {
      float q0v = qs[i0][kk], q1v = qs[i0 + 1][kk];
      float k0v = ts[jj0][kk], k1v = ts[jj0 + 1][kk];
      a00 += q0v * k0v; a01 += q0v * k1v;
      a10 += q1v * k0v; a11 += q1v * k1v;
    }
    a00 = msk[jj0][i0]         ? NEG_ : a00 * SCALE_;
    a01 = msk[jj0 + 1][i0]     ? NEG_ : a01 * SCALE_;
    a10 = msk[jj0][i0 + 1]     ? NEG_ : a10 * SCALE_;
    a11 = msk[jj0 + 1][i0 + 1] ? NEG_ : a11 * SCALE_;
    sp[i0][jj0] = a00; sp[i0][jj0 + 1] = a01;
    sp[i0 + 1][jj0] = a10; sp[i0 + 1][jj0 + 1] = a11;
    __syncthreads();
    // online softmax update (16 threads per row; disjoint j = jl+16k)
    {
      int i = tid >> 4, jl = tid & 15;
      float mx = fmaxf(fmaxf(sp[i][jl], sp[i][jl + 16]),
                       fmaxf(sp[i][jl + 32], sp[i][jl + 48]));
#pragma unroll
      for (int o = 8; o >= 1; o >>= 1) mx = fmaxf(mx, __shfl_xor(mx, o, 16));
      float mold = rowM[i];
      float mnew = fmaxf(mold, mx);
      float s = 0;
#pragma unroll
      for (int j = jl; j < 64; j += 16) {
        float p = expf(sp[i][j] - mnew);
        sp[i][j] = p;
        s += p;
      }
#pragma unroll
      for (int o = 8; o >= 1; o >>= 1) s += __shfl_xor(s, o, 16);
      if (jl == 0) {
        float al = (mold == -INFINITY) ? 0.f : expf(mold - mnew);
        alpha_s[i] = al;
        rowL[i] = rowL[i] * al + s;
        rowM[i] = mnew;
      }
    }
    __syncthreads();
    // numerator weights: multiply by krd (coalesced in n)
    for (int e = tid; e < 16 * 64; e += 256) {
      int i = e >> 6, j = e & 63;
      sp[i][j] *= krd0[(size_t)i * N_ + j0 + j];
    }
    __syncthreads();
    // o update
    float ala = alpha_s[g], alb = alpha_s[g + 8];
    o00 *= ala; o01 *= ala; o10 *= alb; o11 *= alb;
#pragma unroll
    for (int j = 0; j < 64; j++) {
      float pa = sp[g][j], pb = sp[g + 8][j];
      float v0 = vs[j][dd2], v1 = vs[j][dd2 + 1];
      o00 += pa * v0; o01 += pa * v1;
      o10 += pb * v0; o11 += pb * v1;
    }
  }
  float inva = 1.f / rowL[g], invb = 1.f / rowL[g + 8];
  size_t kb = ((size_t)b * M_ + m0) * DIM_ + (size_t)h * D_;
  km[kb + (size_t)g * DIM_ + dd2] = o00 * inva;
  km[kb + (size_t)g * DIM_ + dd2 + 1] = o01 * inva;
  km[kb + (size_t)(g + 8) * DIM_ + dd2] = o10 * invb;
  km[kb + (size_t)(g + 8) * DIM_ + dd2 + 1] = o11 * invb;
}

// ---------------------------------------------------------------------------
// Branch 3: one cluster query per (b,h) vs kernel keys.
// ---------------------------------------------------------------------------
__global__ __launch_bounds__(256) void branch3(
    const float* __restrict__ cq, const float* __restrict__ kkp,
    const float* __restrict__ kvp, const int* __restrict__ mask,
    float* __restrict__ cm) {
  const int h = blockIdx.x, b = blockIdx.y;
  __shared__ float q[64];
  __shared__ float p[512];
  __shared__ float wr1[4], wr2[4];
  __shared__ float ored[4][64];
  const size_t bh = (size_t)b * H_ + h;
  const float* cq0 = cq + bh * D_;
  const float* kk0 = kkp + bh * M_ * D_;
  const float* kv0 = kvp + bh * M_ * D_;
  const int* mask0 = mask + bh * N_ * M_;  // row n = 0
  const int tid = threadIdx.x;
  if (tid < 64) q[tid] = cq0[tid];
  __syncthreads();
  for (int j = tid; j < 512; j += 256) {
    float acc = 0;
    for (int kk = 0; kk < 64; kk++) acc += q[kk] * kk0[(size_t)j * D_ + kk];
    acc *= SCALE_;
    if (mask0[j]) acc = NEG_;
    p[j] = acc;
  }
  __syncthreads();
  float mx = fmaxf(p[tid], p[tid + 256]);
#pragma unroll
  for (int o = 32; o >= 1; o >>= 1) mx = fmaxf(mx, __shfl_xor(mx, o, 64));
  if ((tid & 63) == 0) wr1[tid >> 6] = mx;
  __syncthreads();
  mx = fmaxf(fmaxf(wr1[0], wr1[1]), fmaxf(wr1[2], wr1[3]));
  float e0 = expf(p[tid] - mx), e1 = expf(p[tid + 256] - mx);
  float s = e0 + e1;
#pragma unroll
  for (int o = 32; o >= 1; o >>= 1) s += __shfl_xor(s, o, 64);
  p[tid] = e0; p[tid + 256] = e1;
  if ((tid & 63) == 0) wr2[tid >> 6] = s;
  __syncthreads();
  float invS = 1.f / (wr2[0] + wr2[1] + wr2[2] + wr2[3]);
  int dd = tid & 63, gg = tid >> 6;
  float o = 0;
  for (int j = gg; j < 512; j += 4) o += p[j] * kv0[(size_t)j * D_ + dd];
  ored[gg][dd] = o;
  __syncthreads();
  if (gg == 0) {
    float r = (ored[0][dd] + ored[1][dd] + ored[2][dd] + ored[3][dd]) * invS;
    cm[(size_t)b * DIM_ + (size_t)h * D_ + dd] = r;
  }
}

// ---------------------------------------------------------------------------
extern "C" void kernel_launch(void* const* d_in, const int* in_sizes, int n_in,
                              void* d_out, int out_size, void* d_ws,
                              size_t ws_size, hipStream_t stream) {
  const float* x = (const float*)d_in[0];
  const float* kx = (const float*)d_in[1];
  const float* krd = (const float*)d_in[2];
  const float* clst = (const float*)d_in[3];
  const int* mask = (const int*)d_in[4];
  const float* Wqkv = (const float*)d_in[5];
  const float* Wout = (const float*)d_in[6];
  const float* bout = (const float*)d_in[7];

  float* ws = (float*)d_ws;
  float* t_q = ws;                    // [B,H,N,D]  6291456
  float* t_k = t_q + 6291456;
  float* t_v = t_k + 6291456;
  float* k_q = t_v + 6291456;         // [B,H,M,D]  1572864
  float* k_k = k_q + 1572864;
  float* k_v = k_k + 1572864;
  float* c_q = k_v + 1572864;         // [B,H,1,D]  3072
  float* c_k = c_q + 3072;            // discarded
  float* c_v = c_k + 3072;            // discarded
  float* att_m = c_v + 3072;          // [B,N,768]  6291456
  float* k_m = att_m + 6291456;       // [B,M,768]  1572864
  float* c_m = k_m + 1572864;         // [B,768]    3072

  float* out0 = (float*)d_out;        // [B,N,768]
  float* out1 = out0 + 6291456;       // [B,M,768]
  float* out2 = out1 + 1572864;       // [B,1,768]
  float* out3 = out2 + 3072;          // [B,H,M,N]

  qkv_gemm<<<dim3(36, 128), 256, 0, stream>>>(x, Wqkv, N_, B_ * N_, t_q, t_k, t_v);
  qkv_gemm<<<dim3(36, 32), 256, 0, stream>>>(kx, Wqkv, M_, B_ * M_, k_q, k_k, k_v);
  qkv_gemm<<<dim3(36, 1), 256, 0, stream>>>(clst, Wqkv, 1, B_, c_q, c_k, c_v);

  branch1<<<dim3(N_ / 16, H_, B_), 256, 0, stream>>>(t_q, k_k, k_v, krd, mask,
                                                     out3, att_m);
  branch2<<<dim3(M_ / 16, H_, B_), 256, 0, stream>>>(k_q, t_k, t_v, krd, mask,
                                                     k_m);
  branch3<<<dim3(H_, B_), 256, 0, stream>>>(c_q, k_k, k_v, mask, c_m);

  proj_gemm<<<dim3(12, 128), 256, 0, stream>>>(att_m, Wout, bout, out0, B_ * N_);
  proj_gemm<<<dim3(12, 32), 256, 0, stream>>>(k_m, Wout, bout, out1, B_ * M_);
  proj_gemm<<<dim3(12, 1), 256, 0, stream>>>(c_m, Wout, bout, out2, B_);
}

// Round 2
// 1559.941 us; speedup vs baseline: 1.7982x; 1.7982x over previous
//
#include <hip/hip_runtime.h>
#include <hip/hip_bf16.h>
#include <cmath>
#include <cstdint>

#define B_ 4
#define N_ 2048
#define M_ 512
#define H_ 12
#define D_ 64
#define DIM_ 768
#define QKV_ 2304
#define SCALE_ 0.125f
#define NEG_ -1e9f
#define TEMP_ 24.0f

typedef __attribute__((ext_vector_type(8))) short bf16x8;
typedef __attribute__((ext_vector_type(4))) float f32x4;

__device__ __forceinline__ short f2bf(float f) {
  union { float f; unsigned u; } v; v.f = f;
  unsigned r = v.u + 0x7fffu + ((v.u >> 16) & 1u);
  return (short)(r >> 16);
}
__device__ __forceinline__ float bf2f(short s) {
  union { unsigned u; float f; } v; v.u = ((unsigned)(unsigned short)s) << 16;
  return v.f;
}
#define MFMA16(a, b, c) __builtin_amdgcn_mfma_f32_16x16x32_bf16(a, b, c, 0, 0, 0)

// ---------------------------------------------------------------------------
// Transpose + split W [K][Ncols] fp32 -> Wt_h/Wt_l [Ncols][K] bf16.
// ---------------------------------------------------------------------------
__global__ __launch_bounds__(256) void wsplit_t(
    const float* __restrict__ W, int K, int Ncols,
    short* __restrict__ Wt_h, short* __restrict__ Wt_l) {
  __shared__ float t[32][33];
  const int n0 = blockIdx.x * 32, k0 = blockIdx.y * 32;
  const int tid = threadIdx.x;
  for (int e = tid; e < 1024; e += 256) {
    int r = e >> 5, c = e & 31;
    t[r][c] = W[(size_t)(k0 + r) * Ncols + n0 + c];
  }
  __syncthreads();
  for (int e = tid; e < 1024; e += 256) {
    int r = e >> 5, c = e & 31;  // r = n-local, c = k-local
    float f = t[c][r];
    short hi = f2bf(f);
    short lo = f2bf(f - bf2f(hi));
    size_t o = (size_t)(n0 + r) * K + k0 + c;
    Wt_h[o] = hi; Wt_l[o] = lo;
  }
}

// ---------------------------------------------------------------------------
// QKV GEMM (MFMA, split-bf16): A[rows,768] fp32 @ Wt^T -> q/k hi/lo bf16
// [B,H,rows,64] and v transposed bf16 [B,H,64,rows]. Tile 128x128, 4 waves.
// ---------------------------------------------------------------------------
__global__ __launch_bounds__(256) void qkv_mfma(
    const float* __restrict__ A, const short* __restrict__ Wth,
    const short* __restrict__ Wtl, int rowsPerB, int totalRows,
    short* __restrict__ qh, short* __restrict__ ql,
    short* __restrict__ kh, short* __restrict__ kl,
    short* __restrict__ vt) {
  __shared__ __align__(16) short As_h[128 * 40], As_l[128 * 40];
  __shared__ __align__(16) short Bs_h[128 * 40], Bs_l[128 * 40];
  const int r0 = blockIdx.y * 128, c0 = blockIdx.x * 128;
  const int tid = threadIdx.x;
  const int w = tid >> 6, ln = tid & 63, q = ln >> 4, l15 = ln & 15;
  const int wM = (w & 1) * 64, wN = (w >> 1) * 64;
  const f32x4 z = {0.f, 0.f, 0.f, 0.f};
  f32x4 acc[4][4];
  for (int i = 0; i < 4; i++)
    for (int j = 0; j < 4; j++) acc[i][j] = z;
  for (int k0 = 0; k0 < DIM_; k0 += 32) {
    for (int e = tid; e < 1024; e += 256) {  // A: 128 rows x 8 float4
      int row = e >> 3, c = e & 7;
      int ar = r0 + row; if (ar >= totalRows) ar = totalRows - 1;
      float4 f = *(const float4*)(A + (size_t)ar * DIM_ + k0 + c * 4);
      short h0 = f2bf(f.x), h1 = f2bf(f.y), h2 = f2bf(f.z), h3 = f2bf(f.w);
      short l0 = f2bf(f.x - bf2f(h0)), l1 = f2bf(f.y - bf2f(h1));
      short l2 = f2bf(f.z - bf2f(h2)), l3 = f2bf(f.w - bf2f(h3));
      int o = row * 40 + c * 4;
      *(short4*)(As_h + o) = make_short4(h0, h1, h2, h3);
      *(short4*)(As_l + o) = make_short4(l0, l1, l2, l3);
    }
    for (int e = tid; e < 512; e += 256) {  // B: 128 n-rows x 4 uint4
      int row = e >> 2, c = e & 3;
      size_t go = (size_t)(c0 + row) * DIM_ + k0 + c * 8;
      int o = row * 40 + c * 8;
      *(uint4*)(Bs_h + o) = *(const uint4*)(Wth + go);
      *(uint4*)(Bs_l + o) = *(const uint4*)(Wtl + go);
    }
    __syncthreads();
    bf16x8 ah[4], al[4], bhf[4], blf[4];
    for (int mt = 0; mt < 4; mt++) {
      int o = (wM + mt * 16 + l15) * 40 + q * 8;
      ah[mt] = *(const bf16x8*)(As_h + o);
      al[mt] = *(const bf16x8*)(As_l + o);
    }
    for (int nt = 0; nt < 4; nt++) {
      int o = (wN + nt * 16 + l15) * 40 + q * 8;
      bhf[nt] = *(const bf16x8*)(Bs_h + o);
      blf[nt] = *(const bf16x8*)(Bs_l + o);
    }
    for (int mt = 0; mt < 4; mt++)
      for (int nt = 0; nt < 4; nt++) {
        f32x4 c = acc[mt][nt];
        c = MFMA16(ah[mt], bhf[nt], c);
        c = MFMA16(ah[mt], blf[nt], c);
        c = MFMA16(al[mt], bhf[nt], c);
        acc[mt][nt] = c;
      }
    __syncthreads();
  }
  for (int mt = 0; mt < 4; mt++)
    for (int nt = 0; nt < 4; nt++)
      for (int r = 0; r < 4; r++) {
        int gr = r0 + wM + mt * 16 + q * 4 + r;
        if (gr >= totalRows) continue;
        int gc = c0 + wN + nt * 16 + l15;
        int which = gc / DIM_;
        int rem = gc - which * DIM_;
        int hh = rem >> 6, d = rem & 63;
        int b = gr / rowsPerB, n = gr - b * rowsPerB;
        float v = acc[mt][nt][r];
        short hi = f2bf(v);
        if (which == 2) {
          vt[(((size_t)b * H_ + hh) * 64 + d) * rowsPerB + n] = hi;
        } else {
          short lo = f2bf(v - bf2f(hi));
          size_t o = (((size_t)b * H_ + hh) * rowsPerB + n) * 64 + d;
          if (which == 0) { qh[o] = hi; ql[o] = lo; }
          else           { kh[o] = hi; kl[o] = lo; }
        }
      }
}

// ---------------------------------------------------------------------------
// Output projection (MFMA, split-bf16): A hi/lo bf16 [rows,768] @ Wot^T + b.
// ---------------------------------------------------------------------------
__global__ __launch_bounds__(256) void proj_mfma(
    const short* __restrict__ Ahp, const short* __restrict__ Alp,
    const short* __restrict__ Bth, const short* __restrict__ Btl,
    const float* __restrict__ bias, float* __restrict__ C, int totalRows) {
  __shared__ __align__(16) short As_h[128 * 40], As_l[128 * 40];
  __shared__ __align__(16) short Bs_h[128 * 40], Bs_l[128 * 40];
  const int r0 = blockIdx.y * 128, c0 = blockIdx.x * 128;
  const int tid = threadIdx.x;
  const int w = tid >> 6, ln = tid & 63, q = ln >> 4, l15 = ln & 15;
  const int wM = (w & 1) * 64, wN = (w >> 1) * 64;
  const f32x4 z = {0.f, 0.f, 0.f, 0.f};
  f32x4 acc[4][4];
  for (int i = 0; i < 4; i++)
    for (int j = 0; j < 4; j++) acc[i][j] = z;
  for (int k0 = 0; k0 < DIM_; k0 += 32) {
    for (int e = tid; e < 512; e += 256) {
      int row = e >> 2, c = e & 3;
      int ar = r0 + row; if (ar >= totalRows) ar = totalRows - 1;
      size_t ga = (size_t)ar * DIM_ + k0 + c * 8;
      size_t gb = (size_t)(c0 + row) * DIM_ + k0 + c * 8;
      int o = row * 40 + c * 8;
      *(uint4*)(As_h + o) = *(const uint4*)(Ahp + ga);
      *(uint4*)(As_l + o) = *(const uint4*)(Alp + ga);
      *(uint4*)(Bs_h + o) = *(const uint4*)(Bth + gb);
      *(uint4*)(Bs_l + o) = *(const uint4*)(Btl + gb);
    }
    __syncthreads();
    bf16x8 ah[4], al[4], bhf[4], blf[4];
    for (int mt = 0; mt < 4; mt++) {
      int o = (wM + mt * 16 + l15) * 40 + q * 8;
      ah[mt] = *(const bf16x8*)(As_h + o);
      al[mt] = *(const bf16x8*)(As_l + o);
    }
    for (int nt = 0; nt < 4; nt++) {
      int o = (wN + nt * 16 + l15) * 40 + q * 8;
      bhf[nt] = *(const bf16x8*)(Bs_h + o);
      blf[nt] = *(const bf16x8*)(Bs_l + o);
    }
    for (int mt = 0; mt < 4; mt++)
      for (int nt = 0; nt < 4; nt++) {
        f32x4 c = acc[mt][nt];
        c = MFMA16(ah[mt], bhf[nt], c);
        c = MFMA16(ah[mt], blf[nt], c);
        c = MFMA16(al[mt], bhf[nt], c);
        acc[mt][nt] = c;
      }
    __syncthreads();
  }
  for (int mt = 0; mt < 4; mt++)
    for (int nt = 0; nt < 4; nt++)
      for (int r = 0; r < 4; r++) {
        int gr = r0 + wM + mt * 16 + q * 4 + r;
        if (gr >= totalRows) continue;
        int gc = c0 + wN + nt * 16 + l15;
        C[(size_t)gr * DIM_ + gc] = acc[mt][nt][r] + bias[gc];
      }
}

// ---------------------------------------------------------------------------
// Branch 1 (MFMA): per (b,h,16 n-rows): QK^T split-bf16, two softmaxes over
// M=512, out3 write, P(hi/lo) @ V -> att_m hi/lo. Scores in LDS; P overlays
// the score region via register staging.
// ---------------------------------------------------------------------------
__global__ __launch_bounds__(256) void branch1_mfma(
    const short* __restrict__ tqh, const short* __restrict__ tql,
    const short* __restrict__ kkh, const short* __restrict__ kkl,
    const short* __restrict__ kvt, const float* __restrict__ krd,
    const int* __restrict__ mask, float* __restrict__ out3,
    short* __restrict__ amh, short* __restrict__ aml) {
  __shared__ __align__(16) float sc[16 * 520];  // 33280 B, aliased by P2h/P2l
  __shared__ float rowM[16], inv1[16], inv2[16];
  short* P2h = (short*)sc;          // [16][520]
  short* P2l = P2h + 16 * 520;
  const int b = blockIdx.z, h = blockIdx.y, n0 = blockIdx.x * 16;
  const size_t bhi = (size_t)b * H_ + h;
  const int tid = threadIdx.x;
  const int w = tid >> 6, ln = tid & 63, q = ln >> 4, l15 = ln & 15;
  const float* krd0 = krd + bhi * M_ * N_;
  const int* mask0 = mask + (bhi * N_ + n0) * M_;
  // ---- QK^T ----
  {
    const short* ap = tqh + ((bhi * N_ + n0 + l15) * D_ + q * 8);
    const short* ap2 = tql + ((bhi * N_ + n0 + l15) * D_ + q * 8);
    bf16x8 ah0 = *(const bf16x8*)(ap);
    bf16x8 ah1 = *(const bf16x8*)(ap + 32);
    bf16x8 al0 = *(const bf16x8*)(ap2);
    bf16x8 al1 = *(const bf16x8*)(ap2 + 32);
    for (int t = 0; t < 8; t++) {
      int ct = w * 8 + t;
      const short* bp = kkh + ((bhi * M_ + ct * 16 + l15) * D_ + q * 8);
      const short* bp2 = kkl + ((bhi * M_ + ct * 16 + l15) * D_ + q * 8);
      bf16x8 bh0 = *(const bf16x8*)(bp);
      bf16x8 bh1 = *(const bf16x8*)(bp + 32);
      bf16x8 bl0 = *(const bf16x8*)(bp2);
      bf16x8 bl1 = *(const bf16x8*)(bp2 + 32);
      f32x4 a = {0.f, 0.f, 0.f, 0.f};
      a = MFMA16(ah0, bh0, a); a = MFMA16(ah1, bh1, a);
      a = MFMA16(ah0, bl0, a); a = MFMA16(ah1, bl1, a);
      a = MFMA16(al0, bh0, a); a = MFMA16(al1, bh1, a);
      for (int r = 0; r < 4; r++) sc[(q * 4 + r) * 520 + ct * 16 + l15] = a[r];
    }
  }
  __syncthreads();
  // ---- mask + scale + row stats (both denominators) ----
  {
    int i = tid >> 4, jl = tid & 15;
    float mx = -INFINITY;
    for (int j = jl; j < M_; j += 16) {
      float dv = sc[i * 520 + j];
      dv = mask0[i * M_ + j] ? NEG_ : dv * SCALE_;
      sc[i * 520 + j] = dv;
      mx = fmaxf(mx, dv);
    }
    for (int o = 8; o >= 1; o >>= 1) mx = fmaxf(mx, __shfl_xor(mx, o, 16));
    float s1 = 0.f, s2 = 0.f;
    for (int j = jl; j < M_; j += 16) {
      float dv = sc[i * 520 + j] - mx;
      s1 += __expf(dv * TEMP_);
      s2 += __expf(dv);
    }
    for (int o = 8; o >= 1; o >>= 1) {
      s1 += __shfl_xor(s1, o, 16);
      s2 += __shfl_xor(s2, o, 16);
    }
    if (jl == 0) { rowM[i] = mx; inv1[i] = 1.f / s1; inv2[i] = 1.f / s2; }
  }
  __syncthreads();
  // ---- P build: out3 write + P2 hi/lo (overlay sc via register staging) ----
  {
    const int i = tid & 15;
    float rv[32];
    for (int t = 0; t < 32; t++) rv[t] = sc[i * 520 + (tid >> 4) + 16 * t];
    __syncthreads();
    float mx = rowM[i], v1 = inv1[i], v2 = inv2[i];
    for (int t = 0; t < 32; t++) {
      int j = (tid >> 4) + 16 * t;
      float dv = rv[t];
      float kr = krd0[(size_t)j * N_ + n0 + i];
      out3[(bhi * M_ + j) * N_ + n0 + i] = __expf((dv - mx) * TEMP_) * v1 * kr;
      float p2 = __expf(dv - mx) * v2 * kr;
      short hi = f2bf(p2);
      short lo = f2bf(p2 - bf2f(hi));
      P2h[i * 520 + j] = hi;
      P2l[i * 520 + j] = lo;
    }
  }
  __syncthreads();
  // ---- PV ----
  {
    const int dc = w;
    f32x4 o0 = {0.f, 0.f, 0.f, 0.f}, o1 = {0.f, 0.f, 0.f, 0.f};
    const short* vbase = kvt + ((bhi * 64 + dc * 16 + l15) * (size_t)M_ + q * 8);
    for (int kc = 0; kc < 16; kc += 2) {
      bf16x8 pa0 = *(const bf16x8*)(P2h + l15 * 520 + kc * 32 + q * 8);
      bf16x8 pl0 = *(const bf16x8*)(P2l + l15 * 520 + kc * 32 + q * 8);
      bf16x8 bv0 = *(const bf16x8*)(vbase + kc * 32);
      o0 = MFMA16(pa0, bv0, o0);
      o0 = MFMA16(pl0, bv0, o0);
      bf16x8 pa1 = *(const bf16x8*)(P2h + l15 * 520 + (kc + 1) * 32 + q * 8);
      bf16x8 pl1 = *(const bf16x8*)(P2l + l15 * 520 + (kc + 1) * 32 + q * 8);
      bf16x8 bv1 = *(const bf16x8*)(vbase + (kc + 1) * 32);
      o1 = MFMA16(pa1, bv1, o1);
      o1 = MFMA16(pl1, bv1, o1);
    }
    o0 += o1;
    for (int r = 0; r < 4; r++) {
      float v = o0[r];
      short hi = f2bf(v), lo = f2bf(v - bf2f(hi));
      size_t o = ((size_t)b * N_ + n0 + q * 4 + r) * DIM_ + h * 64 + dc * 16 + l15;
      amh[o] = hi; aml[o] = lo;
    }
  }
}

// ---------------------------------------------------------------------------
// Branch 2 (MFMA, flash): per (b,h,32 m-rows), loop n-chunks of 128.
// ---------------------------------------------------------------------------
__global__ __launch_bounds__(256) void branch2_mfma(
    const short* __restrict__ kqh, const short* __restrict__ kql,
    const short* __restrict__ tkh, const short* __restrict__ tkl,
    const short* __restrict__ tvt, const float* __restrict__ krd,
    const int* __restrict__ mask, short* __restrict__ kmh,
    short* __restrict__ kml) {
  __shared__ __align__(16) float sc[32 * 136];  // 17408 B, aliased by P2h/P2l
  __shared__ unsigned char msk[128 * 36];
  __shared__ float rowM[32], rowL[32], alph[32];
  short* P2h = (short*)sc;          // [32][136]
  short* P2l = P2h + 32 * 136;
  const int b = blockIdx.z, h = blockIdx.y, m0 = blockIdx.x * 32;
  const size_t bhi = (size_t)b * H_ + h;
  const int tid = threadIdx.x;
  const int w = tid >> 6, ln = tid & 63, q = ln >> 4, l15 = ln & 15;
  const float* krd0 = krd + (bhi * M_ + m0) * N_;
  const int* mask0 = mask + bhi * N_ * M_ + m0;
  bf16x8 Ah[2][2], Al[2][2];
  for (int mt = 0; mt < 2; mt++)
    for (int kc = 0; kc < 2; kc++) {
      size_t o = (bhi * M_ + m0 + mt * 16 + l15) * D_ + kc * 32 + q * 8;
      Ah[mt][kc] = *(const bf16x8*)(kqh + o);
      Al[mt][kc] = *(const bf16x8*)(kql + o);
    }
  if (tid < 32) { rowM[tid] = -INFINITY; rowL[tid] = 0.f; }
  const f32x4 z = {0.f, 0.f, 0.f, 0.f};
  f32x4 oa[2]; oa[0] = z; oa[1] = z;
  __syncthreads();
  for (int n0 = 0; n0 < N_; n0 += 128) {
    for (int e = tid; e < 1024; e += 256) {  // mask tile [128 n][32 m]
      int n = e >> 3, c = e & 7;
      int4 mv = *(const int4*)(mask0 + (size_t)(n0 + n) * M_ + c * 4);
      unsigned char* mp = msk + n * 36 + c * 4;
      mp[0] = mv.x != 0; mp[1] = mv.y != 0; mp[2] = mv.z != 0; mp[3] = mv.w != 0;
    }
    for (int t = 0; t < 2; t++) {  // QK: wave w -> ct = 2w+t
      int ct = w * 2 + t;
      const short* bp = tkh + ((bhi * N_ + n0 + ct * 16 + l15) * D_ + q * 8);
      const short* bp2 = tkl + ((bhi * N_ + n0 + ct * 16 + l15) * D_ + q * 8);
      bf16x8 bh0 = *(const bf16x8*)(bp), bh1 = *(const bf16x8*)(bp + 32);
      bf16x8 bl0 = *(const bf16x8*)(bp2), bl1 = *(const bf16x8*)(bp2 + 32);
      for (int mt = 0; mt < 2; mt++) {
        f32x4 a = {0.f, 0.f, 0.f, 0.f};
        a = MFMA16(Ah[mt][0], bh0, a); a = MFMA16(Ah[mt][1], bh1, a);
        a = MFMA16(Ah[mt][0], bl0, a); a = MFMA16(Ah[mt][1], bl1, a);
        a = MFMA16(Al[mt][0], bh0, a); a = MFMA16(Al[mt][1], bh1, a);
        for (int r = 0; r < 4; r++)
          sc[(mt * 16 + q * 4 + r) * 136 + ct * 16 + l15] = a[r];
      }
    }
    __syncthreads();
    {  // online softmax: 8 threads/row
      int i = tid >> 3, jl = tid & 7;
      float mx = -INFINITY;
      for (int j = jl; j < 128; j += 8) {
        float s = sc[i * 136 + j];
        s = msk[j * 36 + i] ? NEG_ : s * SCALE_;
        sc[i * 136 + j] = s;
        mx = fmaxf(mx, s);
      }
      for (int o = 4; o >= 1; o >>= 1) mx = fmaxf(mx, __shfl_xor(mx, o, 8));
      float mold = rowM[i];
      float mnew = fmaxf(mold, mx);
      float sum = 0.f;
      for (int j = jl; j < 128; j += 8) {
        float p = __expf(sc[i * 136 + j] - mnew);
        sc[i * 136 + j] = p;
        sum += p;
      }
      for (int o = 4; o >= 1; o >>= 1) sum += __shfl_xor(sum, o, 8);
      if (jl == 0) {
        float al = (mold == -INFINITY) ? 0.f : __expf(mold - mnew);
        alph[i] = al;
        rowL[i] = rowL[i] * al + sum;
        rowM[i] = mnew;
      }
    }
    __syncthreads();
    {  // P2 = p * krd, hi/lo (overlay sc via register staging)
      float rv[16];
      const int j = tid & 127;
      for (int t = 0; t < 16; t++) rv[t] = sc[((tid >> 7) + 2 * t) * 136 + j];
      __syncthreads();
      for (int t = 0; t < 16; t++) {
        int i = (tid >> 7) + 2 * t;
        float p2 = rv[t] * krd0[(size_t)i * N_ + n0 + j];
        short hi = f2bf(p2), lo = f2bf(p2 - bf2f(hi));
        P2h[i * 136 + j] = hi;
        P2l[i * 136 + j] = lo;
      }
    }
    __syncthreads();
    {  // PV accumulate, wave w -> dc = w
      for (int mt = 0; mt < 2; mt++) {
        f32x4 t = oa[mt];
        for (int r = 0; r < 4; r++) t[r] *= alph[mt * 16 + q * 4 + r];
        for (int kc = 0; kc < 4; kc++) {
          bf16x8 pa = *(const bf16x8*)(P2h + (mt * 16 + l15) * 136 + kc * 32 + q * 8);
          bf16x8 pl = *(const bf16x8*)(P2l + (mt * 16 + l15) * 136 + kc * 32 + q * 8);
          bf16x8 bv = *(const bf16x8*)(tvt + ((bhi * 64 + w * 16 + l15) * (size_t)N_ + n0 + kc * 32 + q * 8));
          t = MFMA16(pa, bv, t);
          t = MFMA16(pl, bv, t);
        }
        oa[mt] = t;
      }
    }
    __syncthreads();
  }
  for (int mt = 0; mt < 2; mt++)
    for (int r = 0; r < 4; r++) {
      int row = mt * 16 + q * 4 + r;
      float v = oa[mt][r] / rowL[row];
      short hi = f2bf(v), lo = f2bf(v - bf2f(hi));
      size_t o = ((size_t)b * M_ + m0 + row) * DIM_ + h * 64 + w * 16 + l15;
      kmh[o] = hi; kml[o] = lo;
    }
}

// ---------------------------------------------------------------------------
// Branch 3: cluster query per (b,h), vector math from hi/lo inputs.
// ---------------------------------------------------------------------------
__global__ __launch_bounds__(256) void branch3_k(
    const short* __restrict__ cqh, const short* __restrict__ cql,
    const short* __restrict__ kkh, const short* __restrict__ kkl,
    const short* __restrict__ kvt, const int* __restrict__ mask,
    short* __restrict__ cmh, short* __restrict__ cml) {
  const int h = blockIdx.x, b = blockIdx.y;
  __shared__ float qv[64];
  __shared__ float p[512];
  __shared__ float wr1[4], wr2[4];
  __shared__ float ored[4][64];
  const size_t bhi = (size_t)b * H_ + h;
  const int tid = threadIdx.x;
  if (tid < 64) qv[tid] = bf2f(cqh[bhi * 64 + tid]) + bf2f(cql[bhi * 64 + tid]);
  __syncthreads();
  const int* mask0 = mask + bhi * N_ * M_;  // row n = 0
  for (int j = tid; j < 512; j += 256) {
    float acc = 0;
    for (int kk = 0; kk < 64; kk++)
      acc += qv[kk] * (bf2f(kkh[(bhi * M_ + j) * 64 + kk]) +
                       bf2f(kkl[(bhi * M_ + j) * 64 + kk]));
    acc *= SCALE_;
    if (mask0[j]) acc = NEG_;
    p[j] = acc;
  }
  __syncthreads();
  float mx = fmaxf(p[tid], p[tid + 256]);
  for (int o = 32; o >= 1; o >>= 1) mx = fmaxf(mx, __shfl_xor(mx, o, 64));
  if ((tid & 63) == 0) wr1[tid >> 6] = mx;
  __syncthreads();
  mx = fmaxf(fmaxf(wr1[0], wr1[1]), fmaxf(wr1[2], wr1[3]));
  float e0 = __expf(p[tid] - mx), e1 = __expf(p[tid + 256] - mx);
  float s = e0 + e1;
  for (int o = 32; o >= 1; o >>= 1) s += __shfl_xor(s, o, 64);
  p[tid] = e0; p[tid + 256] = e1;
  if ((tid & 63) == 0) wr2[tid >> 6] = s;
  __syncthreads();
  float invS = 1.f / (wr2[0] + wr2[1] + wr2[2] + wr2[3]);
  int dd = tid & 63, gg = tid >> 6;
  float o = 0;
  for (int j = gg; j < 512; j += 4)
    o += p[j] * bf2f(kvt[(bhi * 64 + dd) * (size_t)M_ + j]);
  ored[gg][dd] = o;
  __syncthreads();
  if (gg == 0) {
    float r = (ored[0][dd] + ored[1][dd] + ored[2][dd] + ored[3][dd]) * invS;
    short hi = f2bf(r), lo = f2bf(r - bf2f(hi));
    cmh[(size_t)b * DIM_ + h * 64 + dd] = hi;
    cml[(size_t)b * DIM_ + h * 64 + dd] = lo;
  }
}

// ---------------------------------------------------------------------------
extern "C" void kernel_launch(void* const* d_in, const int* in_sizes, int n_in,
                              void* d_out, int out_size, void* d_ws,
                              size_t ws_size, hipStream_t stream) {
  const float* x = (const float*)d_in[0];
  const float* kx = (const float*)d_in[1];
  const float* krd = (const float*)d_in[2];
  const float* clst = (const float*)d_in[3];
  const int* mask = (const int*)d_in[4];
  const float* Wqkv = (const float*)d_in[5];
  const float* Wout = (const float*)d_in[6];
  const float* bout = (const float*)d_in[7];

  short* p = (short*)d_ws;
  auto alloc = [&](size_t n) { short* r = p; p += n; return r; };
  short* Wq_h = alloc(2304ull * 768); short* Wq_l = alloc(2304ull * 768);
  short* Wo_h = alloc(768ull * 768);  short* Wo_l = alloc(768ull * 768);
  short* tq_h = alloc(6291456); short* tq_l = alloc(6291456);
  short* tk_h = alloc(6291456); short* tk_l = alloc(6291456);
  short* tv_t = alloc(6291456);
  short* kq_h = alloc(1572864); short* kq_l = alloc(1572864);
  short* kk_h = alloc(1572864); short* kk_l = alloc(1572864);
  short* kv_t = alloc(1572864);
  short* cq_h = alloc(3072); short* cq_l = alloc(3072);
  short* ck_h = alloc(3072); short* ck_l = alloc(3072);
  short* cv_t = alloc(3072);
  short* am_h = alloc(6291456); short* am_l = alloc(6291456);
  short* km_h = alloc(1572864); short* km_l = alloc(1572864);
  short* cm_h = alloc(3072); short* cm_l = alloc(3072);

  float* out0 = (float*)d_out;        // [B,N,768]
  float* out1 = out0 + 6291456;       // [B,M,768]
  float* out2 = out1 + 1572864;       // [B,1,768]
  float* out3 = out2 + 3072;          // [B,H,M,N]

  wsplit_t<<<dim3(72, 24), 256, 0, stream>>>(Wqkv, DIM_, QKV_, Wq_h, Wq_l);
  wsplit_t<<<dim3(24, 24), 256, 0, stream>>>(Wout, DIM_, DIM_, Wo_h, Wo_l);

  qkv_mfma<<<dim3(18, 64), 256, 0, stream>>>(x, Wq_h, Wq_l, N_, B_ * N_,
                                             tq_h, tq_l, tk_h, tk_l, tv_t);
  qkv_mfma<<<dim3(18, 16), 256, 0, stream>>>(kx, Wq_h, Wq_l, M_, B_ * M_,
                                             kq_h, kq_l, kk_h, kk_l, kv_t);
  qkv_mfma<<<dim3(18, 1), 256, 0, stream>>>(clst, Wq_h, Wq_l, 1, B_,
                                            cq_h, cq_l, ck_h, ck_l, cv_t);

  branch1_mfma<<<dim3(N_ / 16, H_, B_), 256, 0, stream>>>(
      tq_h, tq_l, kk_h, kk_l, kv_t, krd, mask, out3, am_h, am_l);
  branch2_mfma<<<dim3(M_ / 32, H_, B_), 256, 0, stream>>>(
      kq_h, kq_l, tk_h, tk_l, tv_t, krd, mask, km_h, km_l);
  branch3_k<<<dim3(H_, B_), 256, 0, stream>>>(cq_h, cq_l, kk_h, kk_l, kv_t,
                                              mask, cm_h, cm_l);

  proj_mfma<<<dim3(6, 64), 256, 0, stream>>>(am_h, am_l, Wo_h, Wo_l, bout,
                                             out0, B_ * N_);
  proj_mfma<<<dim3(6, 16), 256, 0, stream>>>(km_h, km_l, Wo_h, Wo_l, bout,
                                             out1, B_ * M_);
  proj_mfma<<<dim3(6, 1), 256, 0, stream>>>(cm_h, cm_l, Wo_h, Wo_l, bout,
                                            out2, B_);
}